// Round 1
// baseline (312.479 us; speedup 1.0000x reference)
//
#include <hip/hip_runtime.h>

#define SEQ 2048
#define HID 1024
#define NHEAD 16
#define HDIM 64
#define NB 4
#define NTOK (NB * SEQ)   // 8192
#define NQKV (3 * HID)    // 3072
#define LOG2E 1.44269504088896f
#define QSCALE (0.125f * LOG2E)   // folded into gemm0's Q-column epilogue

typedef __attribute__((ext_vector_type(8))) short bf16x8;
typedef __attribute__((ext_vector_type(4))) float f32x4;

// ---------- helpers ----------

__device__ __forceinline__ void glds16(const void* g, void* l) {
  // async global->LDS, 16B per lane; LDS dest = wave-uniform base + lane*16
  __builtin_amdgcn_global_load_lds(
      (const __attribute__((address_space(1))) void*)g,
      (__attribute__((address_space(3))) void*)l, 16, 0, 0);
}

__device__ __forceinline__ ushort f2bf(float f) {
  union { float f; unsigned int u; } a; a.f = f;
  unsigned int u = a.u;
  return (ushort)((u + 0x7fffu + ((u >> 16) & 1u)) >> 16);  // RNE
}

// pack two fp32 -> bf16x2 in ONE VALU op (RNE). T12 primitive; no builtin on
// gfx950, inline asm required. Pure-VALU asm with register operands — deps
// tracked by operands, no sched_barrier needed (rule #18 is for ds_read asm).
__device__ __forceinline__ unsigned int cvtpk(float a, float b) {
  unsigned int r;
  asm("v_cvt_pk_bf16_f32 %0, %1, %2" : "=v"(r) : "v"(a), "v"(b));
  return r;  // lo = bf16(a), hi = bf16(b)
}

// ---------- 1. fused LayerNorm -> bf16 ----------

__global__ __launch_bounds__(256) void ln_kernel(const float* __restrict__ x,
                                                 const float* __restrict__ g,
                                                 const float* __restrict__ be,
                                                 ushort* __restrict__ y) {
  const int row = blockIdx.x;
  const int tid = threadIdx.x;
  const float4 v = ((const float4*)(x + (size_t)row * HID))[tid];
  float s  = v.x + v.y + v.z + v.w;
  float sq = v.x * v.x + v.y * v.y + v.z * v.z + v.w * v.w;
  for (int o = 1; o < 64; o <<= 1) { s += __shfl_xor(s, o, 64); sq += __shfl_xor(sq, o, 64); }
  __shared__ float as_[4], aq_[4];
  const int wv = tid >> 6;
  if ((tid & 63) == 0) { as_[wv] = s; aq_[wv] = sq; }
  __syncthreads();
  s  = as_[0] + as_[1] + as_[2] + as_[3];
  sq = aq_[0] + aq_[1] + aq_[2] + aq_[3];
  const float mu  = s * (1.0f / HID);
  const float var = sq * (1.0f / HID) - mu * mu;
  const float rs  = rsqrtf(var + 1e-12f);
  const float4 gv = ((const float4*)g)[tid];
  const float4 bv = ((const float4*)be)[tid];
  ushort4 o;
  o.x = f2bf((v.x - mu) * rs * gv.x + bv.x);
  o.y = f2bf((v.y - mu) * rs * gv.y + bv.y);
  o.z = f2bf((v.z - mu) * rs * gv.z + bv.z);
  o.w = f2bf((v.w - mu) * rs * gv.w + bv.w);
  ((ushort4*)(y + (size_t)row * HID))[tid] = o;
}

// ---------- 2. transpose + fp32->bf16 convert, both weights in one launch ----------

__global__ __launch_bounds__(256) void transpose_cvt2(const float* __restrict__ W0,
                                                      ushort* __restrict__ T0,
                                                      const float* __restrict__ W1,
                                                      ushort* __restrict__ T1) {
  const float* W; ushort* WT; int C;
  if (blockIdx.z == 0) { W = W0; WT = T0; C = NQKV; }
  else { if (blockIdx.x >= HID / 32) return; W = W1; WT = T1; C = HID; }
  const int R = HID;
  __shared__ float t[32][33];
  const int c0 = blockIdx.x * 32, r0 = blockIdx.y * 32;
  const int tx = threadIdx.x & 31, ty = threadIdx.x >> 5;
  for (int j = 0; j < 4; ++j)
    t[ty + j * 8][tx] = W[(size_t)(r0 + ty + j * 8) * C + c0 + tx];
  __syncthreads();
  for (int j = 0; j < 4; ++j)
    WT[(size_t)(c0 + ty + j * 8) * R + r0 + tx] = f2bf(t[tx][ty + j * 8]);
}

// ---------- 2b. V transpose: qkv V-region [tok][h*64+d] -> Vt[b][h][d][s] ----------

__global__ __launch_bounds__(256) void v_transpose(const ushort* __restrict__ qkv,
                                                   ushort* __restrict__ vt) {
  __shared__ ushort t[64][66];
  const int s0 = blockIdx.x * 64, h = blockIdx.y, b = blockIdx.z;
  const size_t tokbase = (size_t)b * SEQ;
  for (int e = 0; e < 2; ++e) {
    const int c = e * 256 + threadIdx.x;
    const int sr = c >> 3, dc = c & 7;
    *(uint4*)&t[sr][dc * 8] =
        *(const uint4*)(qkv + (tokbase + s0 + sr) * NQKV + 2 * HID + h * HDIM + dc * 8);
  }
  __syncthreads();
  for (int e = 0; e < 2; ++e) {
    const int c = e * 256 + threadIdx.x;
    const int dr = c >> 3, sc = c & 7;
    ushort tmp[8];
    for (int j = 0; j < 8; ++j) tmp[j] = t[sc * 8 + j][dr];
    *(uint4*)(vt + ((size_t)(b * NHEAD + h) * HDIM + dr) * SEQ + s0 + sc * 8) = *(uint4*)tmp;
  }
}

// ---------- 3. GEMM  C[M][N] = A[M][K] * Bt[N][K]^T  (bf16 in, fp32 acc) ----------

template <int MODE>
__global__ __launch_bounds__(256) void gemm_bt(const ushort* __restrict__ A,
                                               const ushort* __restrict__ Bt,
                                               const float* __restrict__ bias,
                                               const float* __restrict__ resid,
                                               ushort* __restrict__ obf,
                                               float* __restrict__ of32,
                                               int M, int N, int K) {
  __shared__ ushort As[128 * 64];
  __shared__ ushort Bs[128 * 64];
  const int tid = threadIdx.x;
  const int lane = tid & 63, wv = tid >> 6;
  const int q = lane >> 4, li = lane & 15;
  const int m0 = blockIdx.y * 128, n0 = blockIdx.x * 128;
  const int wm = (wv >> 1) * 64, wn = (wv & 1) * 64;
  f32x4 acc[4][4] = {};

  for (int kb = 0; kb < K; kb += 64) {
    for (int e = 0; e < 4; ++e) {
      const int chunk = (wv * 4 + e) * 64 + lane;
      const int row = chunk >> 3, slot = chunk & 7;
      const int kc = slot ^ (row & 7);
      glds16(A  + (size_t)(m0 + row) * K + kb + kc * 8, As + (wv * 4 + e) * 512);
      glds16(Bt + (size_t)(n0 + row) * K + kb + kc * 8, Bs + (wv * 4 + e) * 512);
    }
    __syncthreads();
    for (int ks = 0; ks < 2; ++ks) {
      const int kc = ks * 4 + q;
      bf16x8 af[4], bfr[4];
      for (int mi = 0; mi < 4; ++mi) {
        const int row = wm + mi * 16 + li;
        af[mi] = *(const bf16x8*)(As + (row * 8 + (kc ^ (row & 7))) * 8);
      }
      for (int ni = 0; ni < 4; ++ni) {
        const int row = wn + ni * 16 + li;
        bfr[ni] = *(const bf16x8*)(Bs + (row * 8 + (kc ^ (row & 7))) * 8);
      }
      for (int mi = 0; mi < 4; ++mi)
        for (int ni = 0; ni < 4; ++ni)
          acc[mi][ni] = __builtin_amdgcn_mfma_f32_16x16x32_bf16(af[mi], bfr[ni], acc[mi][ni], 0, 0, 0);
    }
    __syncthreads();
  }

  const float qs = (MODE == 0 && n0 < HID) ? QSCALE : 1.0f;
  for (int ni = 0; ni < 4; ++ni) {
    const int col = n0 + wn + ni * 16 + li;
    const float bvs = bias[col] * qs;
    for (int mi = 0; mi < 4; ++mi) {
      for (int r = 0; r < 4; ++r) {
        const int row = m0 + wm + mi * 16 + q * 4 + r;
        const float v = fmaf(acc[mi][ni][r], qs, bvs);
        if (MODE == 0) obf[(size_t)row * N + col] = f2bf(v);
        else           of32[(size_t)row * N + col] = v + resid[(size_t)row * N + col];
      }
    }
  }
}

// ---------- 4. flash attention, S^T formulation, two-tile software pipeline ----------
// R7: the serial chain QK(t)->softmax(t)->PV(t) left both pipes <60% busy
// (MfmaUtil 30, VALUBusy 57, ~4x stall factor). Now: QK(t+1) issues BEFORE
// softmax(t), so next tile's MFMAs crunch while the VALU does the current
// softmax. K double-buffered, V TRIPLE-buffered (V(t) must outlive the
// staging of K/V(t+2)); still exactly 1 barrier per tile, with stage issued
// a full softmax+PV ahead of the barrier that drains it. softmax+PV run in
// two ks-phases (PV ks=0 MFMAs overlap softmax ks=1 VALU; pk liveness
// halves). pack2bf 3-op -> v_cvt_pk_bf16_f32 1-op (T12). Staging via u32
// offsets from uniform base (saddr form) to contain VGPR growth from the
// second score set. Fixed-shift softmax + l-by-matrix-pipe retained.

__global__ __launch_bounds__(256) void flash_attn(const ushort* __restrict__ qkv,
                                                  const ushort* __restrict__ vt,
                                                  const float* __restrict__ mask,
                                                  ushort* __restrict__ outa) {
  __shared__ ushort Kbuf[2][4096];   // 8KB each; [0..1] contiguous = Q staging (16KB) in prologue
  __shared__ ushort Vbuf[3][4096];   // 8KB each, rotating 3-deep
  const int tid = threadIdx.x, lane = tid & 63, wv = tid >> 6;
  const int quad = lane >> 4, li = lane & 15;
  const int wq = wv * 32;
  constexpr int NT = SEQ / 64;       // 32 kv tiles

  // XCD-aware remap: blocks of one (b,h) share an XCD (id%8 assumed XCD-rr)
  const int L = blockIdx.x + 16 * blockIdx.y + 256 * blockIdx.z;  // 0..1023
  const int xcd = L & 7, rrem = L >> 3;
  const int p = (rrem >> 4) * 8 + xcd;      // (b,h) group 0..63
  const int qt = rrem & 15, h = p & 15, b = p >> 4;

  const size_t tokbase = (size_t)b * SEQ;
  const size_t vtbase = (size_t)(b * NHEAD + h) * HDIM * SEQ;
  const float* mrow = mask + (size_t)b * SEQ;

  // per-lane staging offsets (u32, from uniform bases qkv / vt)
  unsigned ksoff[2], vsoff[2];
  for (int e = 0; e < 2; ++e) {
    const int c = (wv * 2 + e) * 64 + lane;
    const int row = c >> 3, slot = c & 7;
    const int kc = slot ^ (row & 7);
    const int gkv = (row & 0x23) | ((row & 0x0c) << 1) | ((row & 0x10) >> 2);
    ksoff[e] = (unsigned)((tokbase + gkv) * NQKV + HID + h * HDIM + kc * 8);
    vsoff[e] = (unsigned)(vtbase + (size_t)row * SEQ + kc * 8);
  }

  auto stage_k = [&](int t, int buf) {
    const unsigned kadd = (unsigned)(t * 64 * NQKV);
    for (int e = 0; e < 2; ++e)
      glds16(qkv + ksoff[e] + kadd, &Kbuf[buf][0] + (wv * 2 + e) * 512);
  };
  auto stage_v = [&](int t, unsigned vs) {
    const unsigned vadd = (unsigned)(t * 64);
    for (int e = 0; e < 2; ++e)
      glds16(vt + vsoff[e] + vadd, &Vbuf[0][0] + vs + (wv * 2 + e) * 512);
  };

  // ---- prologue: Q into Kbuf[0..1] (16KB), V(0) into V slot 0 ----
  for (int e = 0; e < 4; ++e) {
    const int c = (wv * 4 + e) * 64 + lane;
    const int row = c >> 3, slot = c & 7;
    const int kc = slot ^ (row & 7);
    glds16(qkv + (tokbase + qt * 128 + row) * NQKV + h * HDIM + kc * 8,
           &Kbuf[0][0] + (wv * 4 + e) * 512);
  }
  stage_v(0, 0);
  __syncthreads();  // Q, V0 landed

  bf16x8 qf[2][2];
  for (int ks = 0; ks < 2; ++ks) {
    const int kc = ks * 4 + quad;
    for (int nq = 0; nq < 2; ++nq) {
      const int row = wq + nq * 16 + li;
      qf[ks][nq] = *(const bf16x8*)(&Kbuf[0][0] + (row * 8 + (kc ^ (row & 7))) * 8);
    }
  }
  __syncthreads();  // all Q reads done; Kbuf free for K tiles

  // K/V fragment LDS offsets (ushort elements, shared row pattern)
  int koff[2][4];
  for (int ks = 0; ks < 2; ++ks) {
    const int kc = ks * 4 + quad;
    for (int i = 0; i < 4; ++i) {
      const int row = i * 16 + li;
      koff[ks][i] = (row * 8 + (kc ^ (row & 7))) * 8;
    }
  }

  stage_k(0, 0); stage_k(1, 1); stage_v(1, 4096);
  __syncthreads();  // K0, K1, V1 landed

  const unsigned int one2 = 0x3F803F80u;  // bf16 1.0 x2
  bf16x8 ones;
  for (int j = 0; j < 4; ++j) ((unsigned int*)&ones)[j] = one2;
  const f32x4 zero4 = {0.f, 0.f, 0.f, 0.f};

  f32x4 accO[2][4] = {};
  f32x4 accL[2] = {};
  f32x4 scA[2][4], scB[2][4];

  // QK(0) -> scA (reads Kbuf[0]); C-input of ks=0 is the zero constant, so
  // score sets never need explicit re-zeroing anywhere.
  {
    const ushort* Kb = &Kbuf[0][0];
    for (int ks = 0; ks < 2; ++ks) {
      bf16x8 kf[4];
      for (int m = 0; m < 4; ++m) kf[m] = *(const bf16x8*)(Kb + koff[ks][m]);
      for (int nq = 0; nq < 2; ++nq)
        for (int m = 0; m < 4; ++m)
          scA[nq][m] = __builtin_amdgcn_mfma_f32_16x16x32_bf16(
              kf[m], qf[ks][nq], ks == 0 ? zero4 : scA[nq][m], 0, 0, 0);
    }
  }

  unsigned sV0 = 0, sV1 = 4096, sV2 = 8192;  // V slots for t, t+1, t+2 (uniform)

  auto iter = [&](int t, f32x4 (&scC)[2][4], f32x4 (&scN)[2][4]) {
    __syncthreads();  // K(t+1),V(t+1) published; K(t) slot & V(t-1) slot free
    const int kv0 = t * 64;
    // mask for ks=0 rows (live through QK; ks=1 half loaded later)
    float4 mk01[2];
    for (int m = 0; m < 2; ++m)
      mk01[m] = *(const float4*)(mrow + kv0 + quad * 8 + m * 4);
    // stage K(t+2), V(t+2) — earliest issue, drained at NEXT iter's barrier
    if (t + 2 < NT) { stage_k(t + 2, t & 1); stage_v(t + 2, sV2); }
    // QK(t+1) -> scN : MFMA pipe works on next tile while VALU does softmax(t)
    if (t + 1 < NT) {
      const ushort* Kb = &Kbuf[(t + 1) & 1][0];
      for (int ks = 0; ks < 2; ++ks) {
        bf16x8 kf[4];
        for (int m = 0; m < 4; ++m) kf[m] = *(const bf16x8*)(Kb + koff[ks][m]);
        for (int nq = 0; nq < 2; ++nq)
          for (int m = 0; m < 4; ++m)
            scN[nq][m] = __builtin_amdgcn_mfma_f32_16x16x32_bf16(
                kf[m], qf[ks][nq], ks == 0 ? zero4 : scN[nq][m], 0, 0, 0);
      }
    }
    // mask for ks=1 rows (latency covered by softmax phase 0)
    float4 mk23[2];
    for (int m = 0; m < 2; ++m)
      mk23[m] = *(const float4*)(mrow + kv0 + 32 + quad * 8 + m * 4);

    // softmax(t) + PV(t) in two ks-phases (PV ks=0 overlaps softmax ks=1)
    const ushort* Vb = &Vbuf[0][0] + sV0;
    for (int ks = 0; ks < 2; ++ks) {
      bf16x8 vf[4];
      for (int nd = 0; nd < 4; ++nd)
        vf[nd] = *(const bf16x8*)(Vb + koff[ks][nd]);
      unsigned int pk[2][2][2];
      for (int nq = 0; nq < 2; ++nq)
        for (int mm = 0; mm < 2; ++mm) {
          const int m = 2 * ks + mm;
          const float4 mkv = ks == 0 ? mk01[mm] : mk23[mm];
          const float p0 = __builtin_amdgcn_exp2f(fmaf(mkv.x, LOG2E, scC[nq][m][0]));
          const float p1 = __builtin_amdgcn_exp2f(fmaf(mkv.y, LOG2E, scC[nq][m][1]));
          const float p2 = __builtin_amdgcn_exp2f(fmaf(mkv.z, LOG2E, scC[nq][m][2]));
          const float p3 = __builtin_amdgcn_exp2f(fmaf(mkv.w, LOG2E, scC[nq][m][3]));
          pk[nq][mm][0] = cvtpk(p0, p1);
          pk[nq][mm][1] = cvtpk(p2, p3);
        }
      for (int mq = 0; mq < 2; ++mq) {
        bf16x8 pf;
        ((unsigned int*)&pf)[0] = pk[mq][0][0];
        ((unsigned int*)&pf)[1] = pk[mq][0][1];
        ((unsigned int*)&pf)[2] = pk[mq][1][0];
        ((unsigned int*)&pf)[3] = pk[mq][1][1];
        for (int nd = 0; nd < 4; ++nd)
          accO[mq][nd] = __builtin_amdgcn_mfma_f32_16x16x32_bf16(pf, vf[nd], accO[mq][nd], 0, 0, 0);
        accL[mq] = __builtin_amdgcn_mfma_f32_16x16x32_bf16(pf, ones, accL[mq], 0, 0, 0);
      }
    }
    // rotate V slots (wave-uniform scalars)
    const unsigned tmp = sV0; sV0 = sV1; sV1 = sV2; sV2 = tmp;
  };

  for (int t = 0; t < NT; t += 2) {  // static scA/scB swap (rule #20)
    iter(t,     scA, scB);
    iter(t + 1, scB, scA);
  }

  // epilogue: normalize by l (already in accO layout), store bf16
  for (int mq = 0; mq < 2; ++mq)
    for (int r = 0; r < 4; ++r) {
      const float inv = 1.0f / accL[mq][r];
      const size_t tok = tokbase + qt * 128 + wq + mq * 16 + quad * 4 + r;
      for (int nd = 0; nd < 4; ++nd)
        outa[tok * HID + h * HDIM + nd * 16 + li] = f2bf(accO[mq][nd][r] * inv);
    }
}

// ---------- launch ----------

extern "C" void kernel_launch(void* const* d_in, const int* in_sizes, int n_in,
                              void* d_out, int out_size, void* d_ws, size_t ws_size,
                              hipStream_t stream) {
  const float* hidden = (const float*)d_in[0];
  const float* mask   = (const float*)d_in[1];
  const float* gamma  = (const float*)d_in[2];
  const float* beta   = (const float*)d_in[3];
  const float* Wqkv   = (const float*)d_in[4];
  const float* bqkv   = (const float*)d_in[5];
  const float* Wout   = (const float*)d_in[6];
  const float* bout   = (const float*)d_in[7];
  float* out = (float*)d_out;

  char* ws = (char*)d_ws;
  ushort* x_bf  = (ushort*)(ws);                       // 16 MB (dead after gemm0)
  ushort* vtb   = (ushort*)(ws);                       // 16 MB (reuses x_bf region)
  ushort* wqkvT = (ushort*)(ws + ((size_t)16 << 20));  //  6 MB
  ushort* woutT = (ushort*)(ws + ((size_t)22 << 20));  //  2 MB
  ushort* qkvb  = (ushort*)(ws + ((size_t)24 << 20));  // 48 MB
  ushort* attnb = (ushort*)(ws + ((size_t)72 << 20));  // 16 MB

  ln_kernel<<<NTOK, 256, 0, stream>>>(hidden, gamma, beta, x_bf);
  transpose_cvt2<<<dim3(NQKV / 32, HID / 32, 2), 256, 0, stream>>>(Wqkv, wqkvT, Wout, woutT);
  gemm_bt<0><<<dim3(NQKV / 128, NTOK / 128), 256, 0, stream>>>(
      x_bf, wqkvT, bqkv, nullptr, qkvb, nullptr, NTOK, NQKV, HID);
  v_transpose<<<dim3(SEQ / 64, NHEAD, NB), 256, 0, stream>>>(qkvb, vtb);
  flash_attn<<<dim3(SEQ / 128, NHEAD, NB), 256, 0, stream>>>(qkvb, vtb, mask, attnb);
  gemm_bt<1><<<dim3(HID / 128, NTOK / 128), 256, 0, stream>>>(
      attnb, woutT, bout, hidden, nullptr, out, NTOK, HID, HID);
}

// Round 2
// 301.338 us; speedup vs baseline: 1.0370x; 1.0370x over previous
//
#include <hip/hip_runtime.h>

#define SEQ 2048
#define HID 1024
#define NHEAD 16
#define HDIM 64
#define NB 4
#define NTOK (NB * SEQ)   // 8192
#define NQKV (3 * HID)    // 3072
#define LOG2E 1.44269504088896f
#define QSCALE (0.125f * LOG2E)   // folded into gemm0's Q-column epilogue

typedef __attribute__((ext_vector_type(8))) short bf16x8;
typedef __attribute__((ext_vector_type(4))) float f32x4;

// ---------- helpers ----------

__device__ __forceinline__ void glds16(const void* g, void* l) {
  // async global->LDS, 16B per lane; LDS dest = wave-uniform base + lane*16
  __builtin_amdgcn_global_load_lds(
      (const __attribute__((address_space(1))) void*)g,
      (__attribute__((address_space(3))) void*)l, 16, 0, 0);
}

__device__ __forceinline__ ushort f2bf(float f) {
  union { float f; unsigned int u; } a; a.f = f;
  unsigned int u = a.u;
  return (ushort)((u + 0x7fffu + ((u >> 16) & 1u)) >> 16);  // RNE
}

// pack two fp32 -> bf16x2 in ONE VALU op (RNE). T12 primitive; validated in
// R1 (VALU busy-time -18%). Pure-VALU asm, register operands only — deps
// tracked by operands, no sched_barrier needed (rule #18 is for ds_read asm).
__device__ __forceinline__ unsigned int cvtpk(float a, float b) {
  unsigned int r;
  asm("v_cvt_pk_bf16_f32 %0, %1, %2" : "=v"(r) : "v"(a), "v"(b));
  return r;  // lo = bf16(a), hi = bf16(b)
}

// ---------- 1. fused LayerNorm -> bf16 ----------

__global__ __launch_bounds__(256) void ln_kernel(const float* __restrict__ x,
                                                 const float* __restrict__ g,
                                                 const float* __restrict__ be,
                                                 ushort* __restrict__ y) {
  const int row = blockIdx.x;
  const int tid = threadIdx.x;
  const float4 v = ((const float4*)(x + (size_t)row * HID))[tid];
  float s  = v.x + v.y + v.z + v.w;
  float sq = v.x * v.x + v.y * v.y + v.z * v.z + v.w * v.w;
  for (int o = 1; o < 64; o <<= 1) { s += __shfl_xor(s, o, 64); sq += __shfl_xor(sq, o, 64); }
  __shared__ float as_[4], aq_[4];
  const int wv = tid >> 6;
  if ((tid & 63) == 0) { as_[wv] = s; aq_[wv] = sq; }
  __syncthreads();
  s  = as_[0] + as_[1] + as_[2] + as_[3];
  sq = aq_[0] + aq_[1] + aq_[2] + aq_[3];
  const float mu  = s * (1.0f / HID);
  const float var = sq * (1.0f / HID) - mu * mu;
  const float rs  = rsqrtf(var + 1e-12f);
  const float4 gv = ((const float4*)g)[tid];
  const float4 bv = ((const float4*)be)[tid];
  ushort4 o;
  o.x = f2bf((v.x - mu) * rs * gv.x + bv.x);
  o.y = f2bf((v.y - mu) * rs * gv.y + bv.y);
  o.z = f2bf((v.z - mu) * rs * gv.z + bv.z);
  o.w = f2bf((v.w - mu) * rs * gv.w + bv.w);
  ((ushort4*)(y + (size_t)row * HID))[tid] = o;
}

// ---------- 2. transpose + fp32->bf16 convert, both weights in one launch ----------

__global__ __launch_bounds__(256) void transpose_cvt2(const float* __restrict__ W0,
                                                      ushort* __restrict__ T0,
                                                      const float* __restrict__ W1,
                                                      ushort* __restrict__ T1) {
  const float* W; ushort* WT; int C;
  if (blockIdx.z == 0) { W = W0; WT = T0; C = NQKV; }
  else { if (blockIdx.x >= HID / 32) return; W = W1; WT = T1; C = HID; }
  const int R = HID;
  __shared__ float t[32][33];
  const int c0 = blockIdx.x * 32, r0 = blockIdx.y * 32;
  const int tx = threadIdx.x & 31, ty = threadIdx.x >> 5;
  for (int j = 0; j < 4; ++j)
    t[ty + j * 8][tx] = W[(size_t)(r0 + ty + j * 8) * C + c0 + tx];
  __syncthreads();
  for (int j = 0; j < 4; ++j)
    WT[(size_t)(c0 + ty + j * 8) * R + r0 + tx] = f2bf(t[tx][ty + j * 8]);
}

// ---------- 2b. V transpose: qkv V-region [tok][h*64+d] -> Vt[b][h][d][s] ----------

__global__ __launch_bounds__(256) void v_transpose(const ushort* __restrict__ qkv,
                                                   ushort* __restrict__ vt) {
  __shared__ ushort t[64][66];
  const int s0 = blockIdx.x * 64, h = blockIdx.y, b = blockIdx.z;
  const size_t tokbase = (size_t)b * SEQ;
  for (int e = 0; e < 2; ++e) {
    const int c = e * 256 + threadIdx.x;
    const int sr = c >> 3, dc = c & 7;
    *(uint4*)&t[sr][dc * 8] =
        *(const uint4*)(qkv + (tokbase + s0 + sr) * NQKV + 2 * HID + h * HDIM + dc * 8);
  }
  __syncthreads();
  for (int e = 0; e < 2; ++e) {
    const int c = e * 256 + threadIdx.x;
    const int dr = c >> 3, sc = c & 7;
    ushort tmp[8];
    for (int j = 0; j < 8; ++j) tmp[j] = t[sc * 8 + j][dr];
    *(uint4*)(vt + ((size_t)(b * NHEAD + h) * HDIM + dr) * SEQ + s0 + sc * 8) = *(uint4*)tmp;
  }
}

// ---------- 3. GEMM  C[M][N] = A[M][K] * Bt[N][K]^T  (bf16 in, fp32 acc) ----------

template <int MODE>
__global__ __launch_bounds__(256) void gemm_bt(const ushort* __restrict__ A,
                                               const ushort* __restrict__ Bt,
                                               const float* __restrict__ bias,
                                               const float* __restrict__ resid,
                                               ushort* __restrict__ obf,
                                               float* __restrict__ of32,
                                               int M, int N, int K) {
  __shared__ ushort As[128 * 64];
  __shared__ ushort Bs[128 * 64];
  const int tid = threadIdx.x;
  const int lane = tid & 63, wv = tid >> 6;
  const int q = lane >> 4, li = lane & 15;
  const int m0 = blockIdx.y * 128, n0 = blockIdx.x * 128;
  const int wm = (wv >> 1) * 64, wn = (wv & 1) * 64;
  f32x4 acc[4][4] = {};

  for (int kb = 0; kb < K; kb += 64) {
    for (int e = 0; e < 4; ++e) {
      const int chunk = (wv * 4 + e) * 64 + lane;
      const int row = chunk >> 3, slot = chunk & 7;
      const int kc = slot ^ (row & 7);
      glds16(A  + (size_t)(m0 + row) * K + kb + kc * 8, As + (wv * 4 + e) * 512);
      glds16(Bt + (size_t)(n0 + row) * K + kb + kc * 8, Bs + (wv * 4 + e) * 512);
    }
    __syncthreads();
    for (int ks = 0; ks < 2; ++ks) {
      const int kc = ks * 4 + q;
      bf16x8 af[4], bfr[4];
      for (int mi = 0; mi < 4; ++mi) {
        const int row = wm + mi * 16 + li;
        af[mi] = *(const bf16x8*)(As + (row * 8 + (kc ^ (row & 7))) * 8);
      }
      for (int ni = 0; ni < 4; ++ni) {
        const int row = wn + ni * 16 + li;
        bfr[ni] = *(const bf16x8*)(Bs + (row * 8 + (kc ^ (row & 7))) * 8);
      }
      for (int mi = 0; mi < 4; ++mi)
        for (int ni = 0; ni < 4; ++ni)
          acc[mi][ni] = __builtin_amdgcn_mfma_f32_16x16x32_bf16(af[mi], bfr[ni], acc[mi][ni], 0, 0, 0);
    }
    __syncthreads();
  }

  const float qs = (MODE == 0 && n0 < HID) ? QSCALE : 1.0f;
  for (int ni = 0; ni < 4; ++ni) {
    const int col = n0 + wn + ni * 16 + li;
    const float bvs = bias[col] * qs;
    for (int mi = 0; mi < 4; ++mi) {
      for (int r = 0; r < 4; ++r) {
        const int row = m0 + wm + mi * 16 + q * 4 + r;
        const float v = fmaf(acc[mi][ni][r], qs, bvs);
        if (MODE == 0) obf[(size_t)row * N + col] = f2bf(v);
        else           of32[(size_t)row * N + col] = v + resid[(size_t)row * N + col];
      }
    }
  }
}

// ---------- 4. flash attention, S^T formulation + K/V double-buffer ----------
// R8: REVERT to the R6 single-tile schedule (R7's two-tile pipeline regressed:
// +8KB LDS and +32 VGPR cost more inter-wave TLP than the intra-wave overlap
// gained — MfmaUtil never rose). Keep only the R7-validated VALU cuts, plus
// two new ones, all schedule-neutral:
//  (a) cvtpk: bf16 pack 3 ops -> 1 (R1 measured: VALU busy-time -18%)
//  (b) mask folded into the QK^T MFMA C-initializer (ks=0 C-in = mask*LOG2E)
//      — the matrix pipe does the mask add; removes 32 fma/lane-tile and
//      takes mask loads off the softmax dependency chain
//  (c) mask prefetched one tile ahead into regs (static A/B swap, rule #20),
//      *LOG2E applied at prefetch (16 mul, off the critical path)
// softmax VALU: 112 -> 64 ops/lane-tile, remaining dominated by 32 exp2.
// Everything else identical to the 107.5us R6 kernel: 1 barrier/tile,
// l-by-matrix-pipe, sigma-permuted K rows, hoisted offsets, XCD swizzle.

__global__ __launch_bounds__(256) void flash_attn(const ushort* __restrict__ qkv,
                                                  const ushort* __restrict__ vt,
                                                  const float* __restrict__ mask,
                                                  ushort* __restrict__ outa) {
  __shared__ ushort KV[2][8192];   // per buf: [0..4095]=K (sigma rows), [4096..8191]=V^T
  const int tid = threadIdx.x, lane = tid & 63, wv = tid >> 6;
  const int quad = lane >> 4, li = lane & 15;
  const int wq = wv * 32;
  constexpr int NT = SEQ / 64;     // 32 kv tiles

  // XCD-aware remap: blocks of one (b,h) share an XCD (id%8 assumed XCD-rr)
  const int L = blockIdx.x + 16 * blockIdx.y + 256 * blockIdx.z;  // 0..1023
  const int xcd = L & 7, rrem = L >> 3;
  const int p = (rrem >> 4) * 8 + xcd;      // (b,h) group 0..63
  const int qt = rrem & 15, h = p & 15, b = p >> 4;

  const size_t tokbase = (size_t)b * SEQ;
  const size_t vtbase = (size_t)(b * NHEAD + h) * HDIM * SEQ;
  const float* mrow = mask + (size_t)b * SEQ;

  // ---- prologue: stage Q into KV[0] ----
  for (int e = 0; e < 4; ++e) {
    const int c = (wv * 4 + e) * 64 + lane;
    const int row = c >> 3, slot = c & 7;
    const int kc = slot ^ (row & 7);
    glds16(qkv + (tokbase + qt * 128 + row) * NQKV + h * HDIM + kc * 8,
           &KV[0][0] + (wv * 4 + e) * 512);
  }
  __syncthreads();  // Q landed

  // hoist Q fragments to registers (loop-invariant)
  bf16x8 qf[2][2];
  for (int ks = 0; ks < 2; ++ks) {
    const int kc = ks * 4 + quad;
    for (int nq = 0; nq < 2; ++nq) {
      const int row = wq + nq * 16 + li;
      qf[ks][nq] = *(const bf16x8*)(&KV[0][0] + (row * 8 + (kc ^ (row & 7))) * 8);
    }
  }
  __syncthreads();  // all Q reads done; KV[0] may be overwritten

  // hoisted LDS fragment offsets (ushort elements), loop-invariant
  int koff[2][4], voff[2][4];
  for (int ks = 0; ks < 2; ++ks) {
    const int kc = ks * 4 + quad;
    for (int i = 0; i < 4; ++i) {
      const int row = i * 16 + li;
      koff[ks][i] = (row * 8 + (kc ^ (row & 7))) * 8;
      voff[ks][i] = koff[ks][i] + 4096;   // V^T shares the row pattern, +8KB
    }
  }
  // hoisted global staging addresses (per-lane, kv0=0)
  const ushort* ksrc[2];
  const ushort* vsrc[2];
  for (int e = 0; e < 2; ++e) {
    const int c = (wv * 2 + e) * 64 + lane;
    const int row = c >> 3, slot = c & 7;
    const int kc = slot ^ (row & 7);
    const int gkv = (row & 0x23) | ((row & 0x0c) << 1) | ((row & 0x10) >> 2);
    ksrc[e] = qkv + (tokbase + gkv) * NQKV + HID + h * HDIM + kc * 8;
    vsrc[e] = vt + vtbase + (size_t)row * SEQ + kc * 8;
  }

  const unsigned int one2 = 0x3F803F80u;  // bf16 1.0 x2
  bf16x8 ones;
  for (int j = 0; j < 4; ++j) ((unsigned int*)&ones)[j] = one2;

  f32x4 accO[2][4] = {};
  f32x4 accL[2] = {};   // l per q-row, accO C-layout (all 16 n-cols identical)

  auto stage_kv = [&](int t, int buf) {
    const int kv0 = t * 64;
    for (int e = 0; e < 2; ++e) {
      glds16(ksrc[e] + (size_t)kv0 * NQKV, &KV[buf][0] + (wv * 2 + e) * 512);
      glds16(vsrc[e] + kv0,                &KV[buf][4096] + (wv * 2 + e) * 512);
    }
  };

  // mask prefetch: load tile t's mask, pre-scaled by LOG2E (ready as C-init)
  auto mask_fetch = [&](int t, float4 (&mk)[4]) {
    const int kv0 = (t & (NT - 1)) * 64;   // wrap on the final (unused) prefetch
    for (int m = 0; m < 4; ++m) {
      const float4 v = *(const float4*)(mrow + kv0 + (m >> 1) * 32 + quad * 8 + (m & 1) * 4);
      mk[m].x = v.x * LOG2E; mk[m].y = v.y * LOG2E;
      mk[m].z = v.z * LOG2E; mk[m].w = v.w * LOG2E;
    }
  };

  auto compute = [&](int t, int buf, float4 (&mkc)[4], float4 (&mkn)[4]) {
    // prefetch next tile's mask first (consumed next iteration; latency
    // covered by this tile's QK^T + softmax + PV)
    mask_fetch(t + 1, mkn);

    const ushort* Kb = &KV[buf][0];

    // logits^T = K * Q^T + mask*LOG2E  (mask rides in as the ks=0 C-input;
    // register r of the C fragment pairs with mkc[m] component r — same
    // pairing the old fmaf epilogue used)
    f32x4 sc[2][4];
    for (int ks = 0; ks < 2; ++ks) {
      bf16x8 kf[4];
      for (int mkv = 0; mkv < 4; ++mkv)
        kf[mkv] = *(const bf16x8*)(Kb + koff[ks][mkv]);
      for (int nq = 0; nq < 2; ++nq)
        for (int mkv = 0; mkv < 4; ++mkv) {
          const f32x4 cin = (ks == 0)
              ? (f32x4){mkc[mkv].x, mkc[mkv].y, mkc[mkv].z, mkc[mkv].w}
              : sc[nq][mkv];
          sc[nq][mkv] = __builtin_amdgcn_mfma_f32_16x16x32_bf16(kf[mkv], qf[ks][nq], cin, 0, 0, 0);
        }
    }

    // fixed-shift softmax: p = exp2(logit') directly — no fma, no reduction
    unsigned int pk[2][4][2];
    for (int nq = 0; nq < 2; ++nq) {
      for (int mkv = 0; mkv < 4; ++mkv) {
        const float p0 = __builtin_amdgcn_exp2f(sc[nq][mkv][0]);
        const float p1 = __builtin_amdgcn_exp2f(sc[nq][mkv][1]);
        const float p2 = __builtin_amdgcn_exp2f(sc[nq][mkv][2]);
        const float p3 = __builtin_amdgcn_exp2f(sc[nq][mkv][3]);
        pk[nq][mkv][0] = cvtpk(p0, p1);
        pk[nq][mkv][1] = cvtpk(p2, p3);
      }
    }

    // O += P * V ; l += P * 1  (A-frag = pk registers, sigma alignment)
    for (int ks = 0; ks < 2; ++ks) {
      bf16x8 vf[4];
      for (int nd = 0; nd < 4; ++nd)
        vf[nd] = *(const bf16x8*)(Kb + voff[ks][nd]);
      for (int mq = 0; mq < 2; ++mq) {
        bf16x8 pf;
        ((unsigned int*)&pf)[0] = pk[mq][2 * ks][0];
        ((unsigned int*)&pf)[1] = pk[mq][2 * ks][1];
        ((unsigned int*)&pf)[2] = pk[mq][2 * ks + 1][0];
        ((unsigned int*)&pf)[3] = pk[mq][2 * ks + 1][1];
        for (int nd = 0; nd < 4; ++nd)
          accO[mq][nd] = __builtin_amdgcn_mfma_f32_16x16x32_bf16(pf, vf[nd], accO[mq][nd], 0, 0, 0);
        accL[mq] = __builtin_amdgcn_mfma_f32_16x16x32_bf16(pf, ones, accL[mq], 0, 0, 0);
      }
    }
  };

  // ---- main loop: double-buffered, 1 barrier per tile ----
  float4 mkA[4], mkB[4];
  mask_fetch(0, mkA);
  stage_kv(0, 0);
  for (int t = 0; t < NT; t += 2) {  // static mkA/mkB swap (rule #20)
    __syncthreads();              // pf(t)->buf0 landed; reads of buf1 done
    stage_kv(t + 1, 1);
    compute(t, 0, mkA, mkB);
    __syncthreads();              // pf(t+1)->buf1 landed; reads of buf0 done
    if (t + 2 < SEQ / 64) stage_kv(t + 2, 0);
    compute(t + 1, 1, mkB, mkA);
  }

  // epilogue: normalize by l (already in accO layout — no shuffles), store bf16
  for (int mq = 0; mq < 2; ++mq)
    for (int r = 0; r < 4; ++r) {
      const float inv = 1.0f / accL[mq][r];
      const size_t tok = tokbase + qt * 128 + wq + mq * 16 + quad * 4 + r;
      for (int nd = 0; nd < 4; ++nd)
        outa[tok * HID + h * HDIM + nd * 16 + li] = f2bf(accO[mq][nd][r] * inv);
    }
}

// ---------- launch ----------

extern "C" void kernel_launch(void* const* d_in, const int* in_sizes, int n_in,
                              void* d_out, int out_size, void* d_ws, size_t ws_size,
                              hipStream_t stream) {
  const float* hidden = (const float*)d_in[0];
  const float* mask   = (const float*)d_in[1];
  const float* gamma  = (const float*)d_in[2];
  const float* beta   = (const float*)d_in[3];
  const float* Wqkv   = (const float*)d_in[4];
  const float* bqkv   = (const float*)d_in[5];
  const float* Wout   = (const float*)d_in[6];
  const float* bout   = (const float*)d_in[7];
  float* out = (float*)d_out;

  char* ws = (char*)d_ws;
  ushort* x_bf  = (ushort*)(ws);                       // 16 MB (dead after gemm0)
  ushort* vtb   = (ushort*)(ws);                       // 16 MB (reuses x_bf region)
  ushort* wqkvT = (ushort*)(ws + ((size_t)16 << 20));  //  6 MB
  ushort* woutT = (ushort*)(ws + ((size_t)22 << 20));  //  2 MB
  ushort* qkvb  = (ushort*)(ws + ((size_t)24 << 20));  // 48 MB
  ushort* attnb = (ushort*)(ws + ((size_t)72 << 20));  // 16 MB

  ln_kernel<<<NTOK, 256, 0, stream>>>(hidden, gamma, beta, x_bf);
  transpose_cvt2<<<dim3(NQKV / 32, HID / 32, 2), 256, 0, stream>>>(Wqkv, wqkvT, Wout, woutT);
  gemm_bt<0><<<dim3(NQKV / 128, NTOK / 128), 256, 0, stream>>>(
      x_bf, wqkvT, bqkv, nullptr, qkvb, nullptr, NTOK, NQKV, HID);
  v_transpose<<<dim3(SEQ / 64, NHEAD, NB), 256, 0, stream>>>(qkvb, vtb);
  flash_attn<<<dim3(SEQ / 128, NHEAD, NB), 256, 0, stream>>>(qkvb, vtb, mask, attnb);
  gemm_bt<1><<<dim3(HID / 128, NTOK / 128), 256, 0, stream>>>(
      attnb, woutT, bout, hidden, nullptr, out, NTOK, HID, HID);
}

// Round 3
// 299.198 us; speedup vs baseline: 1.0444x; 1.0072x over previous
//
#include <hip/hip_runtime.h>

#define SEQ 2048
#define HID 1024
#define NHEAD 16
#define HDIM 64
#define NB 4
#define NTOK (NB * SEQ)   // 8192
#define NQKV (3 * HID)    // 3072
#define LOG2E 1.44269504088896f
#define QSCALE (0.125f * LOG2E)   // folded into gemm0's Q-column epilogue

typedef __attribute__((ext_vector_type(8))) short bf16x8;
typedef __attribute__((ext_vector_type(4))) float f32x4;

// ---------- helpers ----------

__device__ __forceinline__ void glds16(const void* g, void* l) {
  // async global->LDS, 16B per lane; LDS dest = wave-uniform base + lane*16
  __builtin_amdgcn_global_load_lds(
      (const __attribute__((address_space(1))) void*)g,
      (__attribute__((address_space(3))) void*)l, 16, 0, 0);
}

__device__ __forceinline__ ushort f2bf(float f) {
  union { float f; unsigned int u; } a; a.f = f;
  unsigned int u = a.u;
  return (ushort)((u + 0x7fffu + ((u >> 16) & 1u)) >> 16);  // RNE
}

// pack two fp32 -> bf16x2 in ONE VALU op (RNE). T12 primitive; validated R1/R2
// (VALU busy-time -14%). Pure-VALU asm, register operands only — deps tracked
// by operands, no sched_barrier needed (rule #18 is for ds_read asm).
__device__ __forceinline__ unsigned int cvtpk(float a, float b) {
  unsigned int r;
  asm("v_cvt_pk_bf16_f32 %0, %1, %2" : "=v"(r) : "v"(a), "v"(b));
  return r;  // lo = bf16(a), hi = bf16(b)
}

// ---------- 1. fused LayerNorm -> bf16 ----------

__global__ __launch_bounds__(256) void ln_kernel(const float* __restrict__ x,
                                                 const float* __restrict__ g,
                                                 const float* __restrict__ be,
                                                 ushort* __restrict__ y) {
  const int row = blockIdx.x;
  const int tid = threadIdx.x;
  const float4 v = ((const float4*)(x + (size_t)row * HID))[tid];
  float s  = v.x + v.y + v.z + v.w;
  float sq = v.x * v.x + v.y * v.y + v.z * v.z + v.w * v.w;
  for (int o = 1; o < 64; o <<= 1) { s += __shfl_xor(s, o, 64); sq += __shfl_xor(sq, o, 64); }
  __shared__ float as_[4], aq_[4];
  const int wv = tid >> 6;
  if ((tid & 63) == 0) { as_[wv] = s; aq_[wv] = sq; }
  __syncthreads();
  s  = as_[0] + as_[1] + as_[2] + as_[3];
  sq = aq_[0] + aq_[1] + aq_[2] + aq_[3];
  const float mu  = s * (1.0f / HID);
  const float var = sq * (1.0f / HID) - mu * mu;
  const float rs  = rsqrtf(var + 1e-12f);
  const float4 gv = ((const float4*)g)[tid];
  const float4 bv = ((const float4*)be)[tid];
  ushort4 o;
  o.x = f2bf((v.x - mu) * rs * gv.x + bv.x);
  o.y = f2bf((v.y - mu) * rs * gv.y + bv.y);
  o.z = f2bf((v.z - mu) * rs * gv.z + bv.z);
  o.w = f2bf((v.w - mu) * rs * gv.w + bv.w);
  ((ushort4*)(y + (size_t)row * HID))[tid] = o;
}

// ---------- 2. transpose + fp32->bf16 convert, both weights in one launch ----------

__global__ __launch_bounds__(256) void transpose_cvt2(const float* __restrict__ W0,
                                                      ushort* __restrict__ T0,
                                                      const float* __restrict__ W1,
                                                      ushort* __restrict__ T1) {
  const float* W; ushort* WT; int C;
  if (blockIdx.z == 0) { W = W0; WT = T0; C = NQKV; }
  else { if (blockIdx.x >= HID / 32) return; W = W1; WT = T1; C = HID; }
  const int R = HID;
  __shared__ float t[32][33];
  const int c0 = blockIdx.x * 32, r0 = blockIdx.y * 32;
  const int tx = threadIdx.x & 31, ty = threadIdx.x >> 5;
  for (int j = 0; j < 4; ++j)
    t[ty + j * 8][tx] = W[(size_t)(r0 + ty + j * 8) * C + c0 + tx];
  __syncthreads();
  for (int j = 0; j < 4; ++j)
    WT[(size_t)(c0 + ty + j * 8) * R + r0 + tx] = f2bf(t[tx][ty + j * 8]);
}

// ---------- 2b. V transpose: qkv V-region [tok][h*64+d] -> Vt[b][h][d][s] ----------

__global__ __launch_bounds__(256) void v_transpose(const ushort* __restrict__ qkv,
                                                   ushort* __restrict__ vt) {
  __shared__ ushort t[64][66];
  const int s0 = blockIdx.x * 64, h = blockIdx.y, b = blockIdx.z;
  const size_t tokbase = (size_t)b * SEQ;
  for (int e = 0; e < 2; ++e) {
    const int c = e * 256 + threadIdx.x;
    const int sr = c >> 3, dc = c & 7;
    *(uint4*)&t[sr][dc * 8] =
        *(const uint4*)(qkv + (tokbase + s0 + sr) * NQKV + 2 * HID + h * HDIM + dc * 8);
  }
  __syncthreads();
  for (int e = 0; e < 2; ++e) {
    const int c = e * 256 + threadIdx.x;
    const int dr = c >> 3, sc = c & 7;
    ushort tmp[8];
    for (int j = 0; j < 8; ++j) tmp[j] = t[sc * 8 + j][dr];
    *(uint4*)(vt + ((size_t)(b * NHEAD + h) * HDIM + dr) * SEQ + s0 + sc * 8) = *(uint4*)tmp;
  }
}

// ---------- 3. GEMM  C[M][N] = A[M][K] * Bt[N][K]^T  (bf16 in, fp32 acc) ----------

template <int MODE>
__global__ __launch_bounds__(256) void gemm_bt(const ushort* __restrict__ A,
                                               const ushort* __restrict__ Bt,
                                               const float* __restrict__ bias,
                                               const float* __restrict__ resid,
                                               ushort* __restrict__ obf,
                                               float* __restrict__ of32,
                                               int M, int N, int K) {
  __shared__ ushort As[128 * 64];
  __shared__ ushort Bs[128 * 64];
  const int tid = threadIdx.x;
  const int lane = tid & 63, wv = tid >> 6;
  const int q = lane >> 4, li = lane & 15;
  const int m0 = blockIdx.y * 128, n0 = blockIdx.x * 128;
  const int wm = (wv >> 1) * 64, wn = (wv & 1) * 64;
  f32x4 acc[4][4] = {};

  for (int kb = 0; kb < K; kb += 64) {
    for (int e = 0; e < 4; ++e) {
      const int chunk = (wv * 4 + e) * 64 + lane;
      const int row = chunk >> 3, slot = chunk & 7;
      const int kc = slot ^ (row & 7);
      glds16(A  + (size_t)(m0 + row) * K + kb + kc * 8, As + (wv * 4 + e) * 512);
      glds16(Bt + (size_t)(n0 + row) * K + kb + kc * 8, Bs + (wv * 4 + e) * 512);
    }
    __syncthreads();
    for (int ks = 0; ks < 2; ++ks) {
      const int kc = ks * 4 + q;
      bf16x8 af[4], bfr[4];
      for (int mi = 0; mi < 4; ++mi) {
        const int row = wm + mi * 16 + li;
        af[mi] = *(const bf16x8*)(As + (row * 8 + (kc ^ (row & 7))) * 8);
      }
      for (int ni = 0; ni < 4; ++ni) {
        const int row = wn + ni * 16 + li;
        bfr[ni] = *(const bf16x8*)(Bs + (row * 8 + (kc ^ (row & 7))) * 8);
      }
      for (int mi = 0; mi < 4; ++mi)
        for (int ni = 0; ni < 4; ++ni)
          acc[mi][ni] = __builtin_amdgcn_mfma_f32_16x16x32_bf16(af[mi], bfr[ni], acc[mi][ni], 0, 0, 0);
    }
    __syncthreads();
  }

  const float qs = (MODE == 0 && n0 < HID) ? QSCALE : 1.0f;
  for (int ni = 0; ni < 4; ++ni) {
    const int col = n0 + wn + ni * 16 + li;
    const float bvs = bias[col] * qs;
    for (int mi = 0; mi < 4; ++mi) {
      for (int r = 0; r < 4; ++r) {
        const int row = m0 + wm + mi * 16 + q * 4 + r;
        const float v = fmaf(acc[mi][ni][r], qs, bvs);
        if (MODE == 0) obf[(size_t)row * N + col] = f2bf(v);
        else           of32[(size_t)row * N + col] = v + resid[(size_t)row * N + col];
      }
    }
  }
}

// ---------- 4. flash attention, S^T formulation + K/V double-buffer ----------
// R9 (on the proven R6 schedule; R2's mask-C-init + cvtpk retained):
//  (a) T5 setprio(1) around each MFMA cluster (QK and both PV slices) —
//      catalog m191: +4-7% attn; targets the measured 26% SIMD-idle by
//      letting MFMA-entering waves preempt softmax-issuing waves across
//      the 4 drifting blocks/CU.
//  (b) ks-split epilogue: exp2(rows 0..31) -> PV slice 0 -> exp2(rows
//      32..63) -> PV slice 1. PV-ks0 MFMAs overlap softmax-ks1 VALU;
//      pk liveness halves.
//  (c) saddr staging: u32 per-lane offsets + uniform base (tile stride
//      folded on SALU) instead of per-lane 64-bit pointer arithmetic.
// Everything else identical: 1 barrier/tile, l-by-matrix-pipe, sigma rows,
// hoisted offsets, XCD swizzle, mask*LOG2E prefetched a tile ahead as C-init.

__global__ __launch_bounds__(256) void flash_attn(const ushort* __restrict__ qkv,
                                                  const ushort* __restrict__ vt,
                                                  const float* __restrict__ mask,
                                                  ushort* __restrict__ outa) {
  __shared__ ushort KV[2][8192];   // per buf: [0..4095]=K (sigma rows), [4096..8191]=V^T
  const int tid = threadIdx.x, lane = tid & 63, wv = tid >> 6;
  const int quad = lane >> 4, li = lane & 15;
  const int wq = wv * 32;
  constexpr int NT = SEQ / 64;     // 32 kv tiles

  // XCD-aware remap: blocks of one (b,h) share an XCD (id%8 assumed XCD-rr)
  const int L = blockIdx.x + 16 * blockIdx.y + 256 * blockIdx.z;  // 0..1023
  const int xcd = L & 7, rrem = L >> 3;
  const int p = (rrem >> 4) * 8 + xcd;      // (b,h) group 0..63
  const int qt = rrem & 15, h = p & 15, b = p >> 4;

  const size_t tokbase = (size_t)b * SEQ;
  const size_t vtbase = (size_t)(b * NHEAD + h) * HDIM * SEQ;
  const float* mrow = mask + (size_t)b * SEQ;

  // ---- prologue: stage Q into KV[0] ----
  for (int e = 0; e < 4; ++e) {
    const int c = (wv * 4 + e) * 64 + lane;
    const int row = c >> 3, slot = c & 7;
    const int kc = slot ^ (row & 7);
    glds16(qkv + (tokbase + qt * 128 + row) * NQKV + h * HDIM + kc * 8,
           &KV[0][0] + (wv * 4 + e) * 512);
  }
  __syncthreads();  // Q landed

  // hoist Q fragments to registers (loop-invariant)
  bf16x8 qf[2][2];
  for (int ks = 0; ks < 2; ++ks) {
    const int kc = ks * 4 + quad;
    for (int nq = 0; nq < 2; ++nq) {
      const int row = wq + nq * 16 + li;
      qf[ks][nq] = *(const bf16x8*)(&KV[0][0] + (row * 8 + (kc ^ (row & 7))) * 8);
    }
  }
  __syncthreads();  // all Q reads done; KV[0] may be overwritten

  // hoisted LDS fragment offsets (ushort elements), loop-invariant
  int koff[2][4], voff[2][4];
  for (int ks = 0; ks < 2; ++ks) {
    const int kc = ks * 4 + quad;
    for (int i = 0; i < 4; ++i) {
      const int row = i * 16 + li;
      koff[ks][i] = (row * 8 + (kc ^ (row & 7))) * 8;
      voff[ks][i] = koff[ks][i] + 4096;   // V^T shares the row pattern, +8KB
    }
  }
  // per-lane staging offsets (u32, from uniform bases qkv / vt — saddr form)
  unsigned ksoff[2], vsoff[2];
  for (int e = 0; e < 2; ++e) {
    const int c = (wv * 2 + e) * 64 + lane;
    const int row = c >> 3, slot = c & 7;
    const int kc = slot ^ (row & 7);
    const int gkv = (row & 0x23) | ((row & 0x0c) << 1) | ((row & 0x10) >> 2);
    ksoff[e] = (unsigned)((tokbase + gkv) * NQKV + HID + h * HDIM + kc * 8);
    vsoff[e] = (unsigned)(vtbase + (size_t)row * SEQ + kc * 8);
  }

  const unsigned int one2 = 0x3F803F80u;  // bf16 1.0 x2
  bf16x8 ones;
  for (int j = 0; j < 4; ++j) ((unsigned int*)&ones)[j] = one2;

  f32x4 accO[2][4] = {};
  f32x4 accL[2] = {};   // l per q-row, accO C-layout (all 16 n-cols identical)

  auto stage_kv = [&](int t, int buf) {
    const unsigned ka = (unsigned)(t * (64 * NQKV));
    const unsigned va = (unsigned)(t * 64);
    for (int e = 0; e < 2; ++e) {
      glds16(qkv + ksoff[e] + ka, &KV[buf][0] + (wv * 2 + e) * 512);
      glds16(vt + vsoff[e] + va,  &KV[buf][4096] + (wv * 2 + e) * 512);
    }
  };

  // mask prefetch: load tile t's mask, pre-scaled by LOG2E (ready as C-init)
  auto mask_fetch = [&](int t, float4 (&mk)[4]) {
    const int kv0 = (t & (NT - 1)) * 64;   // wrap on the final (unused) prefetch
    for (int m = 0; m < 4; ++m) {
      const float4 v = *(const float4*)(mrow + kv0 + (m >> 1) * 32 + quad * 8 + (m & 1) * 4);
      mk[m].x = v.x * LOG2E; mk[m].y = v.y * LOG2E;
      mk[m].z = v.z * LOG2E; mk[m].w = v.w * LOG2E;
    }
  };

  auto compute = [&](int t, int buf, float4 (&mkc)[4], float4 (&mkn)[4]) {
    // prefetch next tile's mask first (consumed next iteration; latency
    // covered by this tile's QK^T + softmax + PV)
    mask_fetch(t + 1, mkn);

    const ushort* Kb = &KV[buf][0];

    // C-init quads (mask*LOG2E); same for nq=0/1, hoisted out of MFMA loop
    f32x4 cin[4];
    for (int m = 0; m < 4; ++m)
      cin[m] = (f32x4){mkc[m].x, mkc[m].y, mkc[m].z, mkc[m].w};

    // logits^T = K * Q^T + mask*LOG2E — one setprio-wrapped MFMA cluster
    f32x4 sc[2][4];
    __builtin_amdgcn_s_setprio(1);
    for (int ks = 0; ks < 2; ++ks) {
      bf16x8 kf[4];
      for (int m = 0; m < 4; ++m)
        kf[m] = *(const bf16x8*)(Kb + koff[ks][m]);
      for (int nq = 0; nq < 2; ++nq)
        for (int m = 0; m < 4; ++m)
          sc[nq][m] = __builtin_amdgcn_mfma_f32_16x16x32_bf16(
              kf[m], qf[ks][nq], ks == 0 ? cin[m] : sc[nq][m], 0, 0, 0);
    }
    __builtin_amdgcn_s_setprio(0);

    // ks-split: softmax kv-rows [32ks,32ks+32) then PV slice ks.
    // PV(ks=0) MFMAs overlap softmax(ks=1) VALU; pk liveness halved.
    for (int ks = 0; ks < 2; ++ks) {
      bf16x8 vf[4];
      for (int nd = 0; nd < 4; ++nd)
        vf[nd] = *(const bf16x8*)(Kb + voff[ks][nd]);   // LDS latency hides under exp2
      unsigned int pk[2][2][2];
      for (int nq = 0; nq < 2; ++nq)
        for (int mm = 0; mm < 2; ++mm) {
          const int m = 2 * ks + mm;
          const float p0 = __builtin_amdgcn_exp2f(sc[nq][m][0]);
          const float p1 = __builtin_amdgcn_exp2f(sc[nq][m][1]);
          const float p2 = __builtin_amdgcn_exp2f(sc[nq][m][2]);
          const float p3 = __builtin_amdgcn_exp2f(sc[nq][m][3]);
          pk[nq][mm][0] = cvtpk(p0, p1);
          pk[nq][mm][1] = cvtpk(p2, p3);
        }
      __builtin_amdgcn_s_setprio(1);
      for (int mq = 0; mq < 2; ++mq) {
        bf16x8 pf;
        ((unsigned int*)&pf)[0] = pk[mq][0][0];
        ((unsigned int*)&pf)[1] = pk[mq][0][1];
        ((unsigned int*)&pf)[2] = pk[mq][1][0];
        ((unsigned int*)&pf)[3] = pk[mq][1][1];
        for (int nd = 0; nd < 4; ++nd)
          accO[mq][nd] = __builtin_amdgcn_mfma_f32_16x16x32_bf16(pf, vf[nd], accO[mq][nd], 0, 0, 0);
        accL[mq] = __builtin_amdgcn_mfma_f32_16x16x32_bf16(pf, ones, accL[mq], 0, 0, 0);
      }
      __builtin_amdgcn_s_setprio(0);
    }
  };

  // ---- main loop: double-buffered, 1 barrier per tile ----
  float4 mkA[4], mkB[4];
  mask_fetch(0, mkA);
  stage_kv(0, 0);
  for (int t = 0; t < NT; t += 2) {  // static mkA/mkB swap (rule #20)
    __syncthreads();              // pf(t)->buf0 landed; reads of buf1 done
    stage_kv(t + 1, 1);
    compute(t, 0, mkA, mkB);
    __syncthreads();              // pf(t+1)->buf1 landed; reads of buf0 done
    if (t + 2 < SEQ / 64) stage_kv(t + 2, 0);
    compute(t + 1, 1, mkB, mkA);
  }

  // epilogue: normalize by l (already in accO layout — no shuffles), store bf16
  for (int mq = 0; mq < 2; ++mq)
    for (int r = 0; r < 4; ++r) {
      const float inv = 1.0f / accL[mq][r];
      const size_t tok = tokbase + qt * 128 + wq + mq * 16 + quad * 4 + r;
      for (int nd = 0; nd < 4; ++nd)
        outa[tok * HID + h * HDIM + nd * 16 + li] = f2bf(accO[mq][nd][r] * inv);
    }
}

// ---------- launch ----------

extern "C" void kernel_launch(void* const* d_in, const int* in_sizes, int n_in,
                              void* d_out, int out_size, void* d_ws, size_t ws_size,
                              hipStream_t stream) {
  const float* hidden = (const float*)d_in[0];
  const float* mask   = (const float*)d_in[1];
  const float* gamma  = (const float*)d_in[2];
  const float* beta   = (const float*)d_in[3];
  const float* Wqkv   = (const float*)d_in[4];
  const float* bqkv   = (const float*)d_in[5];
  const float* Wout   = (const float*)d_in[6];
  const float* bout   = (const float*)d_in[7];
  float* out = (float*)d_out;

  char* ws = (char*)d_ws;
  ushort* x_bf  = (ushort*)(ws);                       // 16 MB (dead after gemm0)
  ushort* vtb   = (ushort*)(ws);                       // 16 MB (reuses x_bf region)
  ushort* wqkvT = (ushort*)(ws + ((size_t)16 << 20));  //  6 MB
  ushort* woutT = (ushort*)(ws + ((size_t)22 << 20));  //  2 MB
  ushort* qkvb  = (ushort*)(ws + ((size_t)24 << 20));  // 48 MB
  ushort* attnb = (ushort*)(ws + ((size_t)72 << 20));  // 16 MB

  ln_kernel<<<NTOK, 256, 0, stream>>>(hidden, gamma, beta, x_bf);
  transpose_cvt2<<<dim3(NQKV / 32, HID / 32, 2), 256, 0, stream>>>(Wqkv, wqkvT, Wout, woutT);
  gemm_bt<0><<<dim3(NQKV / 128, NTOK / 128), 256, 0, stream>>>(
      x_bf, wqkvT, bqkv, nullptr, qkvb, nullptr, NTOK, NQKV, HID);
  v_transpose<<<dim3(SEQ / 64, NHEAD, NB), 256, 0, stream>>>(qkvb, vtb);
  flash_attn<<<dim3(SEQ / 128, NHEAD, NB), 256, 0, stream>>>(qkvb, vtb, mask, attnb);
  gemm_bt<1><<<dim3(HID / 128, NTOK / 128), 256, 0, stream>>>(
      attnb, woutT, bout, hidden, nullptr, out, NTOK, HID, HID);
}